// Round 24
// baseline (214.809 us; speedup 1.0000x reference)
//
#include <hip/hip_runtime.h>

typedef short bf8 __attribute__((ext_vector_type(8)));
typedef float f32x4 __attribute__((ext_vector_type(4)));

static __device__ __forceinline__ unsigned short f2bf(float f) {
  unsigned u = __float_as_uint(f);
  unsigned r = u + 0x7FFFu + ((u >> 16) & 1u);
  return (unsigned short)(r >> 16);
}
static __device__ __forceinline__ float bf2f(unsigned short h) {
  return __uint_as_float(((unsigned)h) << 16);
}
static __device__ __forceinline__ unsigned fkey(float f) {
  unsigned u = __float_as_uint(f);
  return (u & 0x80000000u) ? ~u : (u | 0x80000000u);
}
static __device__ __forceinline__ float kdec(unsigned k) {
  unsigned u = (k & 0x80000000u) ? (k & 0x7FFFFFFFu) : ~k;
  return __uint_as_float(u);
}
// bijective XCD-chunked swizzle (m204)
static __device__ __forceinline__ int xcdswz(int h, int nwg) {
  int q = nwg >> 3, r = nwg & 7;
  int xcd = h & 7, w = h >> 3;
  return (xcd < r ? xcd * (q + 1) : r * (q + 1) + (xcd - r) * q) + w;
}
// balanced dual-job XCD chunking (round-16 win)
static __device__ __forceinline__ int xcdbal(int h, int nwg, int nb0) {
  int xcd = h & 7, w = h >> 3;
  int qa = nb0 >> 3, qb = (nwg - nb0) >> 3;
  return (w < qa) ? (xcd * qa + w) : (nb0 + xcd * qb + (w - qa));
}
// masked 9-point window sum over a [32][32] pixel map (LDS or global)
static __device__ __forceinline__ float win9s(const float* __restrict__ b, int m) {
  int mi = m >> 5, mj = m & 31;
  float s = 0.f;
#pragma unroll
  for (int dy = -1; dy <= 1; ++dy) {
    int i = mi + dy; if ((unsigned)i >= 32u) continue;
#pragma unroll
    for (int dx = -1; dx <= 1; ++dx) {
      int jx = mj + dx; if ((unsigned)jx >= 32u) continue;
      s += b[i * 32 + jx];
    }
  }
  return s;
}

// async global->LDS, 16B per lane. lds dest: wave-uniform base + lane*16.
static __device__ __forceinline__ void gload_lds16(const unsigned short* g, unsigned short* l) {
  __builtin_amdgcn_global_load_lds((const __attribute__((address_space(1))) void*)g,
                                   (__attribute__((address_space(3))) void*)l, 16, 0, 0);
}

// unfold(k=3,pad=1,stride=1) value: row d = (cc*3+ki)*3+kj, col m = i*S+j, src [C][S][S]
static __device__ __forceinline__ float uf3(const float* __restrict__ src, int lgS, int d, int m) {
  const int S = 1 << lgS;
  int cc = d / 9;
  int r9 = d - cc * 9;
  int ki = r9 / 3;
  int kj = r9 - ki * 3;
  int i = (m >> lgS) + ki - 1;
  int j = (m & (S - 1)) + kj - 1;
  if ((unsigned)i >= (unsigned)S || (unsigned)j >= (unsigned)S) return 0.f;
  return src[((size_t)cc << (2 * lgS)) + ((size_t)i << lgS) + j];
}

// ---------------- prep dispatch A (smem union) ----------------
// [0,4): bias-map contractions D1/D2; [4,6): scale maps sclw/scu3w;
// [6,1030): pixgram; [1030,1158): rsr2t; [1158,1414): rsr1t;
// [1414,1670): lr3nbT chunk-gather (K-permuted d' = kk*256+cc, coalesced via LDS pixel-slice);
// [1670,2642): W transposes (rows c'-permuted, cols d'-permuted)
__global__ __launch_bounds__(256) void k_prepA(const float* __restrict__ lrsr3, const float* __restrict__ rsr3,
                                               const float* __restrict__ rsr2, const float* __restrict__ rsr1,
                                               const float* __restrict__ W1, const float* __restrict__ W2,
                                               const float* __restrict__ b1, const float* __restrict__ b2,
                                               float* __restrict__ G2,
                                               float* __restrict__ rsr2t, float* __restrict__ rsr1t,
                                               unsigned short* __restrict__ lr3nbT,
                                               unsigned short* __restrict__ W1t, unsigned short* __restrict__ W2t,
                                               float* __restrict__ sclw, float* __restrict__ scu3w,
                                               float* __restrict__ D1, float* __restrict__ D2) {
  __shared__ __align__(16) unsigned char smem[18432];   // max branch need: b1L+b2L
  const int blk = blockIdx.x;
  const int tid = threadIdx.x;
  if (blk < 4) {
    float* b1L = (float*)smem;          // 2304
    float* b2L = b1L + 2304;            // 2304
    const int p = blk * 256 + tid;             // pixel 0..1023
    for (int i = tid; i < 2304; i += 256) { b1L[i] = b1[i]; b2L[i] = b2[i]; }
    __syncthreads();
    float d1a[9] = {}, d2a[9] = {};
    for (int cc = 0; cc < 256; ++cc) {
      float v = lrsr3[(size_t)cc * 1024 + p];
#pragma unroll
      for (int kk = 0; kk < 9; ++kk) {
        d1a[kk] = fmaf(b1L[cc * 9 + kk], v, d1a[kk]);
        d2a[kk] = fmaf(b2L[cc * 9 + kk], v, d2a[kk]);
      }
    }
#pragma unroll
    for (int kk = 0; kk < 9; ++kk) { D1[kk * 1024 + p] = d1a[kk]; D2[kk * 1024 + p] = d2a[kk]; }
  } else if (blk < 6) {
    float* ss = (float*)smem;           // 1024
    const float* src = (blk == 4) ? lrsr3 : rsr3;
    float a4[4] = {0.f, 0.f, 0.f, 0.f};
    for (int cc = 0; cc < 256; ++cc) {
#pragma unroll
      for (int k = 0; k < 4; ++k) {
        float v = src[(size_t)cc * 1024 + k * 256 + tid];
        a4[k] = fmaf(v, v, a4[k]);
      }
    }
#pragma unroll
    for (int k = 0; k < 4; ++k) ss[k * 256 + tid] = a4[k];
    __syncthreads();
    float* dst = (blk == 4) ? sclw : scu3w;
#pragma unroll
    for (int k = 0; k < 4; ++k) {
      int m = k * 256 + tid;
      dst[m] = 1.f / fmaxf(sqrtf(win9s(ss, m)), 1e-12f);
    }
  } else if (blk < 1030) {
    float (*As)[32] = (float(*)[32])smem;            // 2KB
    float (*Bs)[32] = (float(*)[32])(smem + 2048);   // 2KB
    const int px = blk - 6;
    const int m0 = (px >> 5) * 32, n0 = (px & 31) * 32;
    const int tx = tid & 15, ty = tid >> 4;
    float acc[2][2] = {};
    for (int kb = 0; kb < 256; kb += 16) {
      __syncthreads();
      {
        int kk = tid >> 5, mm = tid & 31;
        As[kk][mm] = lrsr3[(size_t)(kb + kk) * 1024 + m0 + mm];
        Bs[kk][mm] = rsr3[(size_t)(kb + kk) * 1024 + n0 + mm];
        int e2 = tid + 256; int kk2 = e2 >> 5, mm2 = e2 & 31;
        As[kk2][mm2] = lrsr3[(size_t)(kb + kk2) * 1024 + m0 + mm2];
        Bs[kk2][mm2] = rsr3[(size_t)(kb + kk2) * 1024 + n0 + mm2];
      }
      __syncthreads();
#pragma unroll
      for (int kk = 0; kk < 16; ++kk) {
        float a0 = As[kk][ty * 2], a1 = As[kk][ty * 2 + 1];
        float b0 = Bs[kk][tx * 2], b1v = Bs[kk][tx * 2 + 1];
        acc[0][0] = fmaf(a0, b0, acc[0][0]); acc[0][1] = fmaf(a0, b1v, acc[0][1]);
        acc[1][0] = fmaf(a1, b0, acc[1][0]); acc[1][1] = fmaf(a1, b1v, acc[1][1]);
      }
    }
#pragma unroll
    for (int i = 0; i < 2; ++i)
#pragma unroll
      for (int jj = 0; jj < 2; ++jj)
        G2[(size_t)(m0 + ty * 2 + i) * 1024 + (n0 + tx * 2 + jj)] = acc[i][jj];
  } else if (blk < 1158) {
    float (*Tt)[65] = (float(*)[65])smem;            // 16.6KB
    const int idx = blk - 1030;
    const int ct = idx & 1, st = idx >> 1;
#pragma unroll
    for (int i = 0; i < 16; ++i) {
      int id = tid + i * 256;
      int r = id >> 6, c = id & 63;
      Tt[r][c] = rsr2[(size_t)(ct * 64 + r) * 4096 + st * 64 + c];
    }
    __syncthreads();
#pragma unroll
    for (int i = 0; i < 16; ++i) {
      int id = tid + i * 256;
      int cc2 = id >> 6, rr = id & 63;
      rsr2t[(size_t)(st * 64 + cc2) * 128 + ct * 64 + rr] = Tt[rr][cc2];
    }
  } else if (blk < 1414) {
    float (*Tt)[65] = (float(*)[65])smem;
    const int st = blk - 1158;
#pragma unroll
    for (int i = 0; i < 16; ++i) {
      int id = tid + i * 256;
      int r = id >> 6, c = id & 63;
      Tt[r][c] = rsr1[(size_t)r * 16384 + st * 64 + c];
    }
    __syncthreads();
#pragma unroll
    for (int i = 0; i < 16; ++i) {
      int id = tid + i * 256;
      int cc2 = id >> 6, rr = id & 63;
      rsr1t[(size_t)(st * 64 + cc2) * 64 + rr] = Tt[rr][cc2];
    }
  } else if (blk < 1670) {
    // lr3nbT chunk-gather, K-permuted: lr3nbT[m][kk*256+cc] = lrsr3[cc][pix(m,kk)] (0 off-grid).
    float (*Px)[33] = (float(*)[33])smem;            // 96*33*4 = 12.7KB
    const int idx = blk - 1414;                      // 0..255
    const int y = idx >> 3;
    const int cs = (idx & 7) * 32;
    for (int e = tid; e < 3072; e += 256) {
      int ccq = e / 96, p = e - ccq * 96;
      int pix = (y - 1) * 32 + p;
      Px[p][ccq] = ((unsigned)pix < 1024u) ? lrsr3[(size_t)(cs + ccq) * 1024 + pix] : 0.f;
    }
    __syncthreads();
    for (int e8 = tid; e8 < 1152; e8 += 256) {
      int ccq0 = (e8 & 3) * 8;
      int r = e8 >> 2;                   // mloc*9 + kk
      int kk = r % 9, mloc = r / 9;
      int ki = kk / 3, kj = kk - ki * 3;
      int xx2 = mloc + kj - 1;
      bf8 v;
      if ((unsigned)xx2 < 32u) {
        const float* row = &Px[ki * 32 + xx2][ccq0];
#pragma unroll
        for (int e = 0; e < 8; ++e) v[e] = (short)f2bf(row[e]);
      } else {
#pragma unroll
        for (int e = 0; e < 8; ++e) v[e] = 0;
      }
      *(bf8*)(lr3nbT + (size_t)(y * 32 + mloc) * 2304 + kk * 256 + cs + ccq0) = v;
    }
  } else {
    // W transposes: output rows c'-permuted, output cols d'-permuted (kk2*256+cc2).
    unsigned short (*Ls)[65] = (unsigned short(*)[65])smem;   // 8.3KB
    int idx = blk - 1670;
    const float* W; unsigned short* Wt; int Cw, c0, kk2, cb2;
    if (idx < 648) {
      W = W1; Wt = W1t; Cw = 1152;
      int t3 = idx / 18; c0 = (idx % 18) * 64;
      kk2 = t3 >> 2; cb2 = (t3 & 3) * 64;
    } else {
      idx -= 648;
      W = W2; Wt = W2t; Cw = 576;
      int t3 = idx / 9; c0 = (idx % 9) * 64;
      kk2 = t3 >> 2; cb2 = (t3 & 3) * 64;
    }
    const int Cch = Cw / 9;
#pragma unroll
    for (int i = 0; i < 16; ++i) {
      int id = tid + i * 256;
      int r = id >> 6, c = id & 63;
      Ls[r][c] = f2bf(W[(size_t)((cb2 + r) * 9 + kk2) * Cw + c0 + c]);
    }
    __syncthreads();
#pragma unroll
    for (int i = 0; i < 16; ++i) {
      int id = tid + i * 256;
      int cc = id >> 6, rr = id & 63;
      int c = c0 + cc;
      Wt[(size_t)((c % 9) * Cch + c / 9) * 2304 + kk2 * 256 + cb2 + rr] = Ls[rr][cc];
    }
  }
}

// ---------------- bf16 MFMA GEMM body: 128x128 tile, BK=64, 4 waves ----------------
// Takes explicit smem pointer (33792B for NBUF=1, 66560B for NBUF=2) so merged kernels union LDS.
// NBUF>=2: counted-vmcnt rotating pipeline — pays ONLY in the co-resident-tail regime
// (few blocks/CU, no neighbor waves to overlap with; cf. m99/m100 null on full GPU).
// EPI 0: store bf16 C (rows >= Msplit scaled by rowscale map).
// EPI 1: per-(colblock,wave-half) partials (unique writer slot = bx*2+wc).
// EPI 2: per-block ninv from partials (LDS prologue), cmax stores.
struct Job {
  const unsigned short* Alo;
  const unsigned short* Ahi;
  const unsigned short* Bt;
  unsigned short* Clo;
  unsigned short* Chi;
  const float* bl;
  const float* bw;
  const float* bbp;
  const float* rowscale;
  float* pnsq;
  float* pbwd;
  float* cmax;
  int Msplit, N, K, nbx, Mtot, npart, which;
};

template <int EPI, int NBUF>
static __device__ __forceinline__ void gemm_body(const Job& j0, const Job& j1, int nb0, int bid,
                                                 unsigned char* smem) {
  unsigned short (*As)[128 * 64] = (unsigned short(*)[128 * 64])smem;
  unsigned short (*Bs)[128 * 64] = (unsigned short(*)[128 * 64])(smem + (size_t)NBUF * 16384);
  unsigned* colkey = (unsigned*)(smem + (size_t)2 * NBUF * 16384);
  float* ninvL = (float*)(smem + (size_t)2 * NBUF * 16384 + 512);

  const bool first = (bid < nb0);
  const Job j = first ? j0 : j1;
  const int local = bid - (first ? 0 : nb0);
  const int by = local / j.nbx;
  const int bx = local - by * j.nbx;
  const int m0 = by * 128, n0 = bx * 128;
  const int K = j.K, N = j.N;

  const unsigned short* Abase = (m0 < j.Msplit)
      ? j.Alo + (size_t)m0 * K
      : j.Ahi + (size_t)(m0 - j.Msplit) * K;

  const int tid = threadIdx.x;
  const int l = tid & 63;
  const int w = tid >> 6;
  const int wr = w >> 1, wc = w & 1;
  if (EPI == 2) {
    if (tid < 128) {
      colkey[tid] = 0u;
      const int r = m0 + tid;
      float nsq = 0.f, bwd = 0.f;
      for (int p = 0; p < j.npart; ++p) {
        nsq += j.pnsq[(size_t)p * j.Mtot + r];
        bwd += j.pbwd[(size_t)p * j.Mtot + r];
      }
      float tq = nsq + 2.f * bwd + j.bbp[j.which];
      ninvL[tid] = 1.f / fmaxf(sqrtf(fmaxf(tq, 0.f)), 1e-12f);
    }
  }

  f32x4 acc[4][4] = {};

  const int srow = w * 32;
  const int lrow = l >> 3;
  const int gcol = ((l & 7) ^ lrow) * 8;
  const int mr = l & 15;
  const int kg = l >> 4;

  const int nt = K >> 6;
  const int snap_kb = n0 + wc * 64;
  unsigned short snap[4][4][4];

  auto stage = [&](int buf, int kb) {
#pragma unroll
    for (int i = 0; i < 4; ++i) {
      int r = srow + i * 8;
      gload_lds16(Abase + (size_t)(r + lrow) * K + kb + gcol, &As[buf][r * 64]);
      gload_lds16(j.Bt + (size_t)(n0 + r + lrow) * K + kb + gcol, &Bs[buf][r * 64]);
    }
  };
  auto compute_tile = [&](int cur) {
#pragma unroll
    for (int ks = 0; ks < 2; ++ks) {
      bf8 af[4], bv[4];
#pragma unroll
      for (int mi = 0; mi < 4; ++mi) {
        const int row = wr * 64 + mi * 16 + mr;
        af[mi] = *(const bf8*)&As[cur][row * 64 + (((ks * 4 + kg) ^ (row & 7)) * 8)];
      }
#pragma unroll
      for (int ni = 0; ni < 4; ++ni) {
        const int row = wc * 64 + ni * 16 + mr;
        bv[ni] = *(const bf8*)&Bs[cur][row * 64 + (((ks * 4 + kg) ^ (row & 7)) * 8)];
      }
      __builtin_amdgcn_s_setprio(1);
#pragma unroll
      for (int mi = 0; mi < 4; ++mi)
#pragma unroll
        for (int ni = 0; ni < 4; ++ni)
          acc[mi][ni] = __builtin_amdgcn_mfma_f32_16x16x32_bf16(af[mi], bv[ni], acc[mi][ni], 0, 0, 0);
      __builtin_amdgcn_s_setprio(0);
    }
  };
  auto do_snap = [&](int cur) {
#pragma unroll
    for (int mi = 0; mi < 4; ++mi)
#pragma unroll
      for (int e = 0; e < 4; ++e) {
        const int row = wr * 64 + mi * 16 + kg * 4 + e;
#pragma unroll
        for (int ni = 0; ni < 4; ++ni) {
          const int slot = ni * 2 + (mr >> 3);
          snap[mi][ni][e] = As[cur][row * 64 + ((slot ^ (row & 7)) * 8) + (mr & 7)];
        }
      }
  };

  if constexpr (NBUF == 1) {
    for (int t = 0; t < nt; ++t) {
      if (t) __syncthreads();
      stage(0, t << 6);
      __syncthreads();
      compute_tile(0);
      if (EPI == 1 && (t << 6) == snap_kb) do_snap(0);
    }
  } else {
    auto waitv = [&](int Wt) {
      if (Wt >= 2)      asm volatile("s_waitcnt vmcnt(16)\ns_barrier" ::: "memory");
      else if (Wt == 1) asm volatile("s_waitcnt vmcnt(8)\ns_barrier" ::: "memory");
      else              asm volatile("s_waitcnt vmcnt(0)\ns_barrier" ::: "memory");
    };
#pragma unroll
    for (int p = 0; p < NBUF; ++p) if (p < nt) stage(p, p << 6);
    { int inflight = (NBUF < nt ? NBUF : nt); waitv(inflight - 1); }
    int cur = 0;
    for (int t = 0; t < nt; ++t) {
      compute_tile(cur);
      if (EPI == 1 && (t << 6) == snap_kb) do_snap(cur);
      if (t + 1 < nt) {
        asm volatile("s_waitcnt lgkmcnt(0)\ns_barrier" ::: "memory");
        if (t + NBUF < nt) stage(cur, (t + NBUF) << 6);
        const int im = (nt - 1 < t + NBUF) ? (nt - 1) : (t + NBUF);
        waitv(im - (t + 1));
        cur = (cur + 1 == NBUF) ? 0 : cur + 1;
      }
    }
  }

  // C/D frag layout: col = mr, row = kg*4 + e (within 16x16)
  const int lr0 = wr * 64;
  const int lc0 = wc * 64;
  if (EPI == 0) {
    const bool hi = (m0 >= j.Msplit);
    unsigned short* Cbase = hi ? j.Chi + (size_t)(m0 - j.Msplit) * N
                               : j.Clo + (size_t)m0 * N;
    float rs[4][4];
#pragma unroll
    for (int mi = 0; mi < 4; ++mi)
#pragma unroll
      for (int e = 0; e < 4; ++e)
        rs[mi][e] = hi ? j.rowscale[m0 - j.Msplit + lr0 + mi * 16 + kg * 4 + e] : 1.f;
#pragma unroll
    for (int mi = 0; mi < 4; ++mi)
#pragma unroll
      for (int ni = 0; ni < 4; ++ni)
#pragma unroll
        for (int e = 0; e < 4; ++e)
          Cbase[(size_t)(lr0 + mi * 16 + kg * 4 + e) * (size_t)N + (n0 + lc0 + ni * 16 + mr)] =
              f2bf(acc[mi][ni][e] * rs[mi][e]);
  } else if (EPI == 1) {
    float rp[4][4] = {};
    float bp[4][4] = {};
#pragma unroll
    for (int ni = 0; ni < 4; ++ni) {
      const float bwv = j.bw[n0 + lc0 + ni * 16 + mr];
#pragma unroll
      for (int mi = 0; mi < 4; ++mi)
#pragma unroll
        for (int e = 0; e < 4; ++e) {
          const float av = bf2f(snap[mi][ni][e]);
          rp[mi][e] += acc[mi][ni][e] * av;
          bp[mi][e] += bwv * av;
        }
    }
#pragma unroll
    for (int off = 1; off < 16; off <<= 1)
#pragma unroll
      for (int mi = 0; mi < 4; ++mi)
#pragma unroll
        for (int e = 0; e < 4; ++e) {
          rp[mi][e] += __shfl_xor(rp[mi][e], off);
          bp[mi][e] += __shfl_xor(bp[mi][e], off);
        }
    if (mr == 0) {
      const size_t slotbase = (size_t)(bx * 2 + wc) * j.Mtot;
#pragma unroll
      for (int mi = 0; mi < 4; ++mi)
#pragma unroll
        for (int e = 0; e < 4; ++e) {
          const int r = m0 + lr0 + mi * 16 + kg * 4 + e;
          j.pnsq[slotbase + r] = rp[mi][e];
          j.pbwd[slotbase + r] = bp[mi][e];
        }
    }
  } else {
    float nv[4][4];
#pragma unroll
    for (int mi = 0; mi < 4; ++mi)
#pragma unroll
      for (int e = 0; e < 4; ++e)
        nv[mi][e] = ninvL[lr0 + mi * 16 + kg * 4 + e];
#pragma unroll
    for (int ni = 0; ni < 4; ++ni) {
      float blv = j.bl[n0 + lc0 + ni * 16 + mr];
      float mx = -3.0e38f;
#pragma unroll
      for (int mi = 0; mi < 4; ++mi)
#pragma unroll
        for (int e = 0; e < 4; ++e) mx = fmaxf(mx, (acc[mi][ni][e] + blv) * nv[mi][e]);
      atomicMax(&colkey[lc0 + ni * 16 + mr], fkey(mx));
    }
    __syncthreads();
    if (tid < 128) j.cmax[(size_t)by * 1024 + n0 + tid] = kdec(colkey[tid]);
  }
}

// ---------------- prep dispatch B (merged with P, NBUF=2 pipelined) ----------------
// [0,218): P GEMM (EPI0, NBUF=2 counted-vmcnt — tail runs on near-empty GPU);
// [218,2522): U2b unfold; [2522,7642): U1b unfold;
// [7642,7722): bw/bb; [7722,8746): r3max; [8746,8750): bl2/bl1 window sums
__global__ __launch_bounds__(256) void k_prepBP(Job pa, Job pb, int nbP0,
                                                const float* __restrict__ rsr2t, const float* __restrict__ rsr1t,
                                                const float* __restrict__ W1, const float* __restrict__ W2,
                                                const float* __restrict__ b1, const float* __restrict__ b2,
                                                const float* __restrict__ sclw, const float* __restrict__ scu3w,
                                                const float* __restrict__ D1, const float* __restrict__ D2,
                                                const float* __restrict__ G2,
                                                unsigned short* __restrict__ U2b, unsigned short* __restrict__ U1b,
                                                float* __restrict__ bw2, float* __restrict__ bw1,
                                                float* __restrict__ bb,
                                                float* __restrict__ bl2, float* __restrict__ bl1,
                                                float* __restrict__ s3, int* __restrict__ arg) {
  __shared__ __align__(16) unsigned char sm[66560];   // NBUF=2 GEMM: 2*2*16384 + 1024
  const int blk = blockIdx.x;
  const int tid = threadIdx.x;
  if (blk < 218) {
    gemm_body<0, 2>(pa, pb, nbP0, xcdswz(blk, 218), sm);
  } else if (blk < 2522) {
    int id = (blk - 218) * 256 + tid;          // < 589824
    int t = id & 15, rest = id >> 4;
    int kk = rest % 9, n = rest / 9;
    int cc0 = t * 8;
    int ki = kk / 3, kj = kk - ki * 3;
    int sy = (n >> 6) + ki - 1, sx = (n & 63) + kj - 1;
    bf8 v;
    if ((unsigned)sy < 64u && (unsigned)sx < 64u) {
      const float* p = rsr2t + (size_t)(sy * 64 + sx) * 128 + cc0;
      f32x4 a = *(const f32x4*)p;
      f32x4 bq = *(const f32x4*)(p + 4);
#pragma unroll
      for (int e = 0; e < 4; ++e) { v[e] = (short)f2bf(a[e]); v[4 + e] = (short)f2bf(bq[e]); }
    } else {
#pragma unroll
      for (int e = 0; e < 8; ++e) v[e] = 0;
    }
    *(bf8*)(U2b + (size_t)n * 1152 + kk * 128 + cc0) = v;
  } else if (blk < 7642) {
    int id = (blk - 2522) * 256 + tid;         // < 1310720
    int n = id / 80, rem = id - n * 80;
    int ks = rem >> 3, t = rem & 7;
    int cc0 = t * 8;
    bf8 v;
    if (ks == 9) {
#pragma unroll
      for (int e = 0; e < 8; ++e) v[e] = 0;
    } else {
      int ki = ks / 3, kj = ks - ki * 3;
      int sy = (n >> 7) + ki - 1, sx = (n & 127) + kj - 1;
      if ((unsigned)sy < 128u && (unsigned)sx < 128u) {
        const float* p = rsr1t + (size_t)(sy * 128 + sx) * 64 + cc0;
        f32x4 a = *(const f32x4*)p;
        f32x4 bq = *(const f32x4*)(p + 4);
#pragma unroll
        for (int e = 0; e < 4; ++e) { v[e] = (short)f2bf(a[e]); v[4 + e] = (short)f2bf(bq[e]); }
      } else {
#pragma unroll
        for (int e = 0; e < 8; ++e) v[e] = 0;
      }
    }
    *(bf8*)(U1b + (size_t)n * 640 + ks * 64 + cc0) = v;
  } else if (blk < 7722) {
    float* red = (float*)sm;
    int idx = blk - 7642;
    int x = idx & 7, y = idx >> 3;             // y < 10
    if (y == 9) {
      if (x >= 2) return;
      const float* b = x ? b2 : b1;
      float s = 0.f;
      for (int d = tid; d < 2304; d += 256) s += b[d] * b[d];
      red[tid] = s; __syncthreads();
      for (int o = 128; o > 0; o >>= 1) { if (tid < o) red[tid] += red[tid + o]; __syncthreads(); }
      if (tid == 0) bb[x] = red[0];
      return;
    }
    const bool two = x < 5;
    const float* W = two ? W1 : W2;
    const float* b = two ? b1 : b2;
    float* bw = two ? bw2 : bw1;
    const int Cw = two ? 1152 : 576;
    int c = (two ? x : x - 5) * 256 + tid;
    if (c >= Cw) return;
    int d0 = y * 256;
    float s = 0.f;
    for (int d = d0; d < d0 + 256; ++d) s += b[d] * W[(size_t)d * Cw + c];
    atomicAdd(&bw[(c % 9) * (Cw / 9) + c / 9], s);   // permuted index
  } else if (blk < 8746) {
    float* bv = (float*)sm;
    int* bidx = (int*)(sm + 1024);
    const int m = blk - 7722;
    const int mi = m >> 5, mj = m & 31;
    float best = -3.0e38f; int bi = 0;
    for (int n = tid; n < 1024; n += 256) {
      const int ni = n >> 5, nj = n & 31;
      float raw = 0.f;
#pragma unroll
      for (int dy = -1; dy <= 1; ++dy) {
#pragma unroll
        for (int dx = -1; dx <= 1; ++dx) {
          bool vm = ((unsigned)(mi + dy) < 32u) && ((unsigned)(mj + dx) < 32u);
          bool vn = ((unsigned)(ni + dy) < 32u) && ((unsigned)(nj + dx) < 32u);
          if (vm && vn) {
            int off = dy * 32 + dx;
            raw += G2[(size_t)(m + off) * 1024 + (n + off)];
          }
        }
      }
      float v = raw * scu3w[n];
      if (v > best) { best = v; bi = n; }
    }
    bv[tid] = best; bidx[tid] = bi;
    __syncthreads();
    for (int o = 128; o > 0; o >>= 1) {
      if (tid < o) {
        float ov = bv[tid + o]; int oi = bidx[tid + o];
        if (ov > bv[tid] || (ov == bv[tid] && oi < bidx[tid])) { bv[tid] = ov; bidx[tid] = oi; }
      }
      __syncthreads();
    }
    if (tid == 0) { s3[m] = bv[0] * sclw[m]; arg[m] = bidx[0]; }
  } else {
    int m = (blk - 8746) * 256 + tid;          // < 1024
    int mi = m >> 5, mj = m & 31;
    float a1 = 0.f, a2 = 0.f;
#pragma unroll
    for (int ki = 0; ki < 3; ++ki) {
      int i = mi + ki - 1; if ((unsigned)i >= 32u) continue;
#pragma unroll
      for (int kj = 0; kj < 3; ++kj) {
        int jx = mj + kj - 1; if ((unsigned)jx >= 32u) continue;
        int pix = i * 32 + jx;
        int kk = ki * 3 + kj;
        a1 += D1[kk * 1024 + pix];
        a2 += D2[kk * 1024 + pix];
      }
    }
    float sc = sclw[m];
    bl2[m] = a1 * sc;
    bl1[m] = a2 * sc;
  }
}

__global__ __launch_bounds__(256) void k_gE1(Job a, Job b, int nb0) {
  __shared__ __align__(16) unsigned char sm[33792];
  gemm_body<1, 1>(a, b, nb0, xcdbal((int)blockIdx.x, (int)gridDim.x, nb0), sm);
}
__global__ __launch_bounds__(256) void k_gE2(Job a, Job b, int nb0) {
  __shared__ __align__(16) unsigned char sm[33792];
  gemm_body<2, 1>(a, b, nb0, xcdbal((int)blockIdx.x, (int)gridDim.x, nb0), sm);
}

// ---------------- fused gather+fold (vectorized) + S1/S2 finalize ----------------
__global__ __launch_bounds__(256) void k_tfold(const float* __restrict__ ref3, const float* __restrict__ ref2,
                                               const float* __restrict__ ref1, const int* __restrict__ arg,
                                               const float* __restrict__ cmax1, const float* __restrict__ cmax2,
                                               float* __restrict__ out) {
  const int bid = blockIdx.x;
  const int tid = threadIdx.x;
  if (bid < 256) {
    __shared__ float plane[1024];
    __shared__ int argL[1024];
    const int c = bid;
#pragma unroll
    for (int k = 0; k < 4; ++k) {
      plane[k * 256 + tid] = ref3[(size_t)c * 1024 + k * 256 + tid];
      argL[k * 256 + tid] = arg[k * 256 + tid];
    }
    __syncthreads();
#pragma unroll
    for (int k = 0; k < 4; ++k) {
      int px = k * 256 + tid;
      int y = px >> 5, x = px & 31;
      float s = 0.f;
#pragma unroll
      for (int di = -1; di <= 1; ++di) {
        int i = y + di;
        if ((unsigned)i >= 32u) continue;
#pragma unroll
        for (int dj = -1; dj <= 1; ++dj) {
          int jw = x + dj;
          if ((unsigned)jw >= 32u) continue;
          int n2 = argL[i * 32 + jw];
          int rr = (n2 >> 5) + y - i, cc = (n2 & 31) + x - jw;
          if ((unsigned)rr < 32u && (unsigned)cc < 32u) s += plane[rr * 32 + cc];
        }
      }
      out[3072 + (size_t)c * 1024 + px] = s * (1.f / 9.f);
    }
  } else if (bid < 1280) {
    __shared__ int argL[1024];
#pragma unroll
    for (int k = 0; k < 4; ++k) argL[k * 256 + tid] = arg[k * 256 + tid];
    __syncthreads();
    int id2 = (bid - 256) * 256 + tid;
    int q = id2 & 31, y = (id2 >> 5) & 63, c = id2 >> 11;
    int iy = y >> 1;
    float s0 = 0.f, s1 = 0.f;
#pragma unroll
    for (int di = -1; di <= 1; ++di) {
      int i = iy + di;
      if ((unsigned)i >= 32u) continue;
      int ry = y - 2 * i;
#pragma unroll
      for (int dj = -1; dj <= 1; ++dj) {
        int jw = q + dj;
        if ((unsigned)jw >= 32u) continue;
        int n2 = argL[i * 32 + jw];
        int rr = (n2 >> 5) * 2 + ry;
        int cb = (n2 & 31) * 2 + 2 * (q - jw);
        if ((unsigned)rr < 64u && (unsigned)cb < 63u) {
          const float* p = ref2 + (size_t)c * 4096 + rr * 64 + cb;
          s0 += p[0]; s1 += p[1];
        }
      }
    }
    float2 o; o.x = s0 * (1.f / 9.f); o.y = s1 * (1.f / 9.f);
    *(float2*)(out + 265216 + (size_t)c * 4096 + y * 64 + 2 * q) = o;
  } else if (bid < 2304) {
    __shared__ int argL[1024];
#pragma unroll
    for (int k = 0; k < 4; ++k) argL[k * 256 + tid] = arg[k * 256 + tid];
    __syncthreads();
    int id1 = (bid - 1280) * 256 + tid;
    int q = id1 & 31, y = (id1 >> 5) & 127, c = id1 >> 12;
    int iy = y >> 2;
    f32x4 s = {0.f, 0.f, 0.f, 0.f};
#pragma unroll
    for (int di = -1; di <= 1; ++di) {
      int i = iy + di;
      if ((unsigned)i >= 32u) continue;
      int ry = y - 4 * i;
#pragma unroll
      for (int dj = -1; dj <= 1; ++dj) {
        int jw = q + dj;
        if ((unsigned)jw >= 32u) continue;
        int n2 = argL[i * 32 + jw];
        int rr = (n2 >> 5) * 4 + ry;
        int cb = (n2 & 31) * 4 + 4 * (q - jw);
        if ((unsigned)rr < 128u && (unsigned)cb < 125u) {
          f32x4 v = *(const f32x4*)(ref1 + (size_t)c * 16384 + rr * 128 + cb);
          s += v;
        }
      }
    }
    s *= (1.f / 9.f);
    *(f32x4*)(out + 789504 + (size_t)c * 16384 + y * 128 + 4 * q) = s;
  } else {
    int t = (bid - 2304) * 256 + tid;  // 0..2047
    if (t < 1024) {
      float mx = -3.0e38f;
      for (int rb = 0; rb < 128; ++rb) mx = fmaxf(mx, cmax1[rb * 1024 + t]);
      out[t] = mx;            // S_1
    } else {
      int tt = t - 1024;
      float mx = -3.0e38f;
      for (int rb = 0; rb < 32; ++rb) mx = fmaxf(mx, cmax2[rb * 1024 + tt]);
      out[1024 + tt] = mx;    // S_2
    }
  }
}

// ---------------- workspace layout (bytes) ----------------
static constexpr size_t OFF_BW2     = 0;                        // 1152 f32
static constexpr size_t OFF_BW1     = 4608;                     // 640 f32
static constexpr size_t ZERO_BYTES  = 7168;
static constexpr size_t OFF_BB      = 7168;                     // 2 f32 (pad to 256)
static constexpr size_t OFF_BL2     = 7424;                     // 1024 f32
static constexpr size_t OFF_BL1     = 11520;                    // 1024 f32
static constexpr size_t OFF_SCLW    = 15616;                    // 1024 f32
static constexpr size_t OFF_SCU3W   = 19712;                    // 1024 f32
static constexpr size_t OFF_R3ARG   = 23808;                    // 1024 int
static constexpr size_t OFF_PNSQ2   = 27904;                    // f32 [18][4096]
static constexpr size_t OFF_PBWD2   = OFF_PNSQ2 + 294912;       // f32 [18][4096]
static constexpr size_t OFF_PNSQ1   = OFF_PBWD2 + 294912;       // f32 [10][16384]
static constexpr size_t OFF_PBWD1   = OFF_PNSQ1 + 655360;       // f32 [10][16384]
static constexpr size_t OFF_CMAX2   = OFF_PBWD1 + 655360;       // f32 [32][1024]
static constexpr size_t OFF_CMAX1   = OFF_CMAX2 + 131072;       // f32 [128][1024]
static constexpr size_t OFF_LR3NBT  = OFF_CMAX1 + 524288;       // bf16 [1024][2304] (RAW, d'-perm)
static constexpr size_t OFF_U2B     = OFF_LR3NBT + 4718592;     // bf16 [4096][1152] (perm K)
static constexpr size_t OFF_U1B     = OFF_U2B    + 9437184;     // bf16 [16384][640] (perm K)
static constexpr size_t OFF_W1T     = OFF_U1B    + 20971520;    // bf16 [1152][2304] (perm rows+cols)
static constexpr size_t OFF_W2T     = OFF_W1T    + 5308416;     // bf16 [640][2304] (perm; 576+ zero)
static constexpr size_t OFF_A2      = OFF_W2T    + 2949120;     // bf16 [1152][1152]
static constexpr size_t OFF_A1      = OFF_A2     + 2654208;     // bf16 [640][640]
static constexpr size_t OFF_M2T     = OFF_A1     + 819200;      // bf16 [1024][1152]
static constexpr size_t OFF_M1T     = OFF_M2T    + 2359296;     // bf16 [1024][640]
static constexpr size_t OFF_G2      = OFF_M1T    + 1310720;     // f32 [1024][1024]
static constexpr size_t OFF_R2T     = OFF_G2     + 4194304;     // f32 [4096][128]
static constexpr size_t OFF_R1T     = OFF_R2T    + 2097152;     // f32 [16384][64]
static constexpr size_t OFF_D1      = OFF_R1T    + 4194304;     // f32 [9][1024]
static constexpr size_t OFF_D2      = OFF_D1     + 36864;       // f32 [9][1024]

extern "C" void kernel_launch(void* const* d_in, const int* in_sizes, int n_in,
                              void* d_out, int out_size, void* d_ws, size_t ws_size,
                              hipStream_t stream) {
  (void)in_sizes; (void)n_in; (void)out_size; (void)ws_size;
  const float* lrsr3  = (const float*)d_in[0];
  const float* rsr1   = (const float*)d_in[1];
  const float* rsr2   = (const float*)d_in[2];
  const float* rsr3   = (const float*)d_in[3];
  const float* ref1   = (const float*)d_in[4];
  const float* ref2   = (const float*)d_in[5];
  const float* ref3   = (const float*)d_in[6];
  const float* W1     = (const float*)d_in[7];
  const float* b1     = (const float*)d_in[8];
  const float* W2     = (const float*)d_in[9];
  const float* b2     = (const float*)d_in[10];
  float* out = (float*)d_out;
  char* ws = (char*)d_ws;

  float*          bw2     = (float*)(ws + OFF_BW2);
  float*          bw1     = (float*)(ws + OFF_BW1);
  float*          bb      = (float*)(ws + OFF_BB);
  float*          bl2     = (float*)(ws + OFF_BL2);
  float*          bl1     = (float*)(ws + OFF_BL1);
  float*          sclw    = (float*)(ws + OFF_SCLW);
  float*          scu3w   = (float*)(ws + OFF_SCU3W);
  int*            R3arg   = (int*)(ws + OFF_R3ARG);
  float*          pnsq2   = (float*)(ws + OFF_PNSQ2);
  float*          pbwd2   = (float*)(ws + OFF_PBWD2);
  float*          pnsq1   = (float*)(ws + OFF_PNSQ1);
  float*          pbwd1   = (float*)(ws + OFF_PBWD1);
  float*          cmax2   = (float*)(ws + OFF_CMAX2);
  float*          cmax1   = (float*)(ws + OFF_CMAX1);
  unsigned short* lr3nbT  = (unsigned short*)(ws + OFF_LR3NBT);
  unsigned short* U2b     = (unsigned short*)(ws + OFF_U2B);
  unsigned short* U1b     = (unsigned short*)(ws + OFF_U1B);
  unsigned short* W1t     = (unsigned short*)(ws + OFF_W1T);
  unsigned short* W2t     = (unsigned short*)(ws + OFF_W2T);
  unsigned short* A2b     = (unsigned short*)(ws + OFF_A2);
  unsigned short* A1b     = (unsigned short*)(ws + OFF_A1);
  unsigned short* M2tb    = (unsigned short*)(ws + OFF_M2T);
  unsigned short* M1tb    = (unsigned short*)(ws + OFF_M1T);
  float*          G2      = (float*)(ws + OFF_G2);
  float*          rsr2t   = (float*)(ws + OFF_R2T);
  float*          rsr1t   = (float*)(ws + OFF_R1T);
  float*          D1      = (float*)(ws + OFF_D1);
  float*          D2      = (float*)(ws + OFF_D2);

  hipMemsetAsync(d_ws, 0, ZERO_BYTES, stream);
  // zero pad rows 576..639 of W2t
  hipMemsetAsync(ws + OFF_W2T + (size_t)576 * 2304 * 2, 0, (size_t)64 * 2304 * 2, stream);

  // A: D-maps || scale maps || pixel Gram || transposes || lr3nbT chunk-gather || W transposes
  k_prepA<<<2642, 256, 0, stream>>>(lrsr3, rsr3, rsr2, rsr1, W1, W2, b1, b2,
                                    G2, rsr2t, rsr1t, lr3nbT, W1t, W2t, sclw, scu3w, D1, D2);

  Job jz = {};
  // B+P: P-GEMM (NBUF=2, row scale = sclw map) || U unfolds || bw/bb || r3max || bl windows
  {
    Job a = jz, b = jz;
    a.Alo = W1t; a.Ahi = lr3nbT; a.Msplit = 1152; a.Bt = W1t;
    a.Clo = A2b; a.Chi = M2tb; a.rowscale = sclw; a.N = 1152; a.K = 2304; a.nbx = 9;
    b.Alo = W2t; b.Ahi = lr3nbT; b.Msplit = 640; b.Bt = W2t;
    b.Clo = A1b; b.Chi = M1tb; b.rowscale = sclw; b.N = 640; b.K = 2304; b.nbx = 5;
    k_prepBP<<<8750, 256, 0, stream>>>(a, b, 153, rsr2t, rsr1t, W1, W2, b1, b2,
                                       sclw, scu3w, D1, D2, G2,
                                       U2b, U1b, bw2, bw1, bb, bl2, bl1, out + 2048, R3arg);
  }
  // E1: per-(colblock,half) norm/bw partials (balanced per-XCD dual-job chunking)
  {
    Job a = jz, b = jz;
    a.Alo = U2b; a.Ahi = U2b; a.Msplit = 4096; a.Bt = A2b;
    a.bw = bw2; a.pnsq = pnsq2; a.pbwd = pbwd2; a.Mtot = 4096;
    a.N = 1152; a.K = 1152; a.nbx = 9;
    b.Alo = U1b; b.Ahi = U1b; b.Msplit = 16384; b.Bt = A1b;
    b.bw = bw1; b.pnsq = pnsq1; b.pbwd = pbwd1; b.Mtot = 16384;
    b.N = 640; b.K = 640; b.nbx = 5;
    k_gE1<<<288 + 640, 256, 0, stream>>>(a, b, 288);
  }
  // E2: score max (per-block ninv from partials; balanced per-XCD dual-job chunking)
  {
    Job a = jz, b = jz;
    a.Alo = U2b; a.Ahi = U2b; a.Msplit = 4096; a.Bt = M2tb;
    a.bl = bl2; a.pnsq = pnsq2; a.pbwd = pbwd2; a.bbp = bb;
    a.npart = 18; a.which = 0; a.cmax = cmax2; a.Mtot = 4096;
    a.N = 1024; a.K = 1152; a.nbx = 8;
    b.Alo = U1b; b.Ahi = U1b; b.Msplit = 16384; b.Bt = M1tb;
    b.bl = bl1; b.pnsq = pnsq1; b.pbwd = pbwd1; b.bbp = bb;
    b.npart = 10; b.which = 1; b.cmax = cmax1; b.Mtot = 16384;
    b.N = 1024; b.K = 640; b.nbx = 8;
    k_gE2<<<256 + 1024, 256, 0, stream>>>(a, b, 256);
  }

  // transfer + S1/S2 finalize (fused, vectorized gathers)
  k_tfold<<<2312, 256, 0, stream>>>(ref3, ref2, ref1, R3arg, cmax1, cmax2, out);
}

// Round 25
// 204.661 us; speedup vs baseline: 1.0496x; 1.0496x over previous
//
#include <hip/hip_runtime.h>

typedef short bf8 __attribute__((ext_vector_type(8)));
typedef float f32x4 __attribute__((ext_vector_type(4)));

static __device__ __forceinline__ unsigned short f2bf(float f) {
  unsigned u = __float_as_uint(f);
  unsigned r = u + 0x7FFFu + ((u >> 16) & 1u);
  return (unsigned short)(r >> 16);
}
static __device__ __forceinline__ float bf2f(unsigned short h) {
  return __uint_as_float(((unsigned)h) << 16);
}
static __device__ __forceinline__ unsigned fkey(float f) {
  unsigned u = __float_as_uint(f);
  return (u & 0x80000000u) ? ~u : (u | 0x80000000u);
}
static __device__ __forceinline__ float kdec(unsigned k) {
  unsigned u = (k & 0x80000000u) ? (k & 0x7FFFFFFFu) : ~k;
  return __uint_as_float(u);
}
// bijective XCD-chunked swizzle (m204)
static __device__ __forceinline__ int xcdswz(int h, int nwg) {
  int q = nwg >> 3, r = nwg & 7;
  int xcd = h & 7, w = h >> 3;
  return (xcd < r ? xcd * (q + 1) : r * (q + 1) + (xcd - r) * q) + w;
}
// balanced dual-job XCD chunking (round-16 win)
static __device__ __forceinline__ int xcdbal(int h, int nwg, int nb0) {
  int xcd = h & 7, w = h >> 3;
  int qa = nb0 >> 3, qb = (nwg - nb0) >> 3;
  return (w < qa) ? (xcd * qa + w) : (nb0 + xcd * qb + (w - qa));
}
// masked 9-point window sum over a [32][32] pixel map (LDS or global)
static __device__ __forceinline__ float win9s(const float* __restrict__ b, int m) {
  int mi = m >> 5, mj = m & 31;
  float s = 0.f;
#pragma unroll
  for (int dy = -1; dy <= 1; ++dy) {
    int i = mi + dy; if ((unsigned)i >= 32u) continue;
#pragma unroll
    for (int dx = -1; dx <= 1; ++dx) {
      int jx = mj + dx; if ((unsigned)jx >= 32u) continue;
      s += b[i * 32 + jx];
    }
  }
  return s;
}

// async global->LDS, 16B per lane. lds dest: wave-uniform base + lane*16.
static __device__ __forceinline__ void gload_lds16(const unsigned short* g, unsigned short* l) {
  __builtin_amdgcn_global_load_lds((const __attribute__((address_space(1))) void*)g,
                                   (__attribute__((address_space(3))) void*)l, 16, 0, 0);
}

// unfold(k=3,pad=1,stride=1) value: row d = (cc*3+ki)*3+kj, col m = i*S+j, src [C][S][S]
static __device__ __forceinline__ float uf3(const float* __restrict__ src, int lgS, int d, int m) {
  const int S = 1 << lgS;
  int cc = d / 9;
  int r9 = d - cc * 9;
  int ki = r9 / 3;
  int kj = r9 - ki * 3;
  int i = (m >> lgS) + ki - 1;
  int j = (m & (S - 1)) + kj - 1;
  if ((unsigned)i >= (unsigned)S || (unsigned)j >= (unsigned)S) return 0.f;
  return src[((size_t)cc << (2 * lgS)) + ((size_t)i << lgS) + j];
}

// ---------------- prep dispatch A (smem union) ----------------
// [0,4): bias-map contractions D1/D2; [4,6): scale maps sclw/scu3w;
// [6,1030): pixgram; [1030,1158): rsr2t; [1158,1414): rsr1t;
// [1414,1670): lr3nbT chunk-gather (K-permuted d' = kk*256+cc, coalesced via LDS pixel-slice);
// [1670,2642): W transposes (rows c'-permuted, cols d'-permuted)
__global__ __launch_bounds__(256) void k_prepA(const float* __restrict__ lrsr3, const float* __restrict__ rsr3,
                                               const float* __restrict__ rsr2, const float* __restrict__ rsr1,
                                               const float* __restrict__ W1, const float* __restrict__ W2,
                                               const float* __restrict__ b1, const float* __restrict__ b2,
                                               float* __restrict__ G2,
                                               float* __restrict__ rsr2t, float* __restrict__ rsr1t,
                                               unsigned short* __restrict__ lr3nbT,
                                               unsigned short* __restrict__ W1t, unsigned short* __restrict__ W2t,
                                               float* __restrict__ sclw, float* __restrict__ scu3w,
                                               float* __restrict__ D1, float* __restrict__ D2) {
  __shared__ __align__(16) unsigned char smem[18432];   // max branch need: b1L+b2L
  const int blk = blockIdx.x;
  const int tid = threadIdx.x;
  if (blk < 4) {
    float* b1L = (float*)smem;          // 2304
    float* b2L = b1L + 2304;            // 2304
    const int p = blk * 256 + tid;             // pixel 0..1023
    for (int i = tid; i < 2304; i += 256) { b1L[i] = b1[i]; b2L[i] = b2[i]; }
    __syncthreads();
    float d1a[9] = {}, d2a[9] = {};
    for (int cc = 0; cc < 256; ++cc) {
      float v = lrsr3[(size_t)cc * 1024 + p];
#pragma unroll
      for (int kk = 0; kk < 9; ++kk) {
        d1a[kk] = fmaf(b1L[cc * 9 + kk], v, d1a[kk]);
        d2a[kk] = fmaf(b2L[cc * 9 + kk], v, d2a[kk]);
      }
    }
#pragma unroll
    for (int kk = 0; kk < 9; ++kk) { D1[kk * 1024 + p] = d1a[kk]; D2[kk * 1024 + p] = d2a[kk]; }
  } else if (blk < 6) {
    float* ss = (float*)smem;           // 1024
    const float* src = (blk == 4) ? lrsr3 : rsr3;
    float a4[4] = {0.f, 0.f, 0.f, 0.f};
    for (int cc = 0; cc < 256; ++cc) {
#pragma unroll
      for (int k = 0; k < 4; ++k) {
        float v = src[(size_t)cc * 1024 + k * 256 + tid];
        a4[k] = fmaf(v, v, a4[k]);
      }
    }
#pragma unroll
    for (int k = 0; k < 4; ++k) ss[k * 256 + tid] = a4[k];
    __syncthreads();
    float* dst = (blk == 4) ? sclw : scu3w;
#pragma unroll
    for (int k = 0; k < 4; ++k) {
      int m = k * 256 + tid;
      dst[m] = 1.f / fmaxf(sqrtf(win9s(ss, m)), 1e-12f);
    }
  } else if (blk < 1030) {
    float (*As)[32] = (float(*)[32])smem;            // 2KB
    float (*Bs)[32] = (float(*)[32])(smem + 2048);   // 2KB
    const int px = blk - 6;
    const int m0 = (px >> 5) * 32, n0 = (px & 31) * 32;
    const int tx = tid & 15, ty = tid >> 4;
    float acc[2][2] = {};
    for (int kb = 0; kb < 256; kb += 16) {
      __syncthreads();
      {
        int kk = tid >> 5, mm = tid & 31;
        As[kk][mm] = lrsr3[(size_t)(kb + kk) * 1024 + m0 + mm];
        Bs[kk][mm] = rsr3[(size_t)(kb + kk) * 1024 + n0 + mm];
        int e2 = tid + 256; int kk2 = e2 >> 5, mm2 = e2 & 31;
        As[kk2][mm2] = lrsr3[(size_t)(kb + kk2) * 1024 + m0 + mm2];
        Bs[kk2][mm2] = rsr3[(size_t)(kb + kk2) * 1024 + n0 + mm2];
      }
      __syncthreads();
#pragma unroll
      for (int kk = 0; kk < 16; ++kk) {
        float a0 = As[kk][ty * 2], a1 = As[kk][ty * 2 + 1];
        float b0 = Bs[kk][tx * 2], b1v = Bs[kk][tx * 2 + 1];
        acc[0][0] = fmaf(a0, b0, acc[0][0]); acc[0][1] = fmaf(a0, b1v, acc[0][1]);
        acc[1][0] = fmaf(a1, b0, acc[1][0]); acc[1][1] = fmaf(a1, b1v, acc[1][1]);
      }
    }
#pragma unroll
    for (int i = 0; i < 2; ++i)
#pragma unroll
      for (int jj = 0; jj < 2; ++jj)
        G2[(size_t)(m0 + ty * 2 + i) * 1024 + (n0 + tx * 2 + jj)] = acc[i][jj];
  } else if (blk < 1158) {
    float (*Tt)[65] = (float(*)[65])smem;            // 16.6KB
    const int idx = blk - 1030;
    const int ct = idx & 1, st = idx >> 1;
#pragma unroll
    for (int i = 0; i < 16; ++i) {
      int id = tid + i * 256;
      int r = id >> 6, c = id & 63;
      Tt[r][c] = rsr2[(size_t)(ct * 64 + r) * 4096 + st * 64 + c];
    }
    __syncthreads();
#pragma unroll
    for (int i = 0; i < 16; ++i) {
      int id = tid + i * 256;
      int cc2 = id >> 6, rr = id & 63;
      rsr2t[(size_t)(st * 64 + cc2) * 128 + ct * 64 + rr] = Tt[rr][cc2];
    }
  } else if (blk < 1414) {
    float (*Tt)[65] = (float(*)[65])smem;
    const int st = blk - 1158;
#pragma unroll
    for (int i = 0; i < 16; ++i) {
      int id = tid + i * 256;
      int r = id >> 6, c = id & 63;
      Tt[r][c] = rsr1[(size_t)r * 16384 + st * 64 + c];
    }
    __syncthreads();
#pragma unroll
    for (int i = 0; i < 16; ++i) {
      int id = tid + i * 256;
      int cc2 = id >> 6, rr = id & 63;
      rsr1t[(size_t)(st * 64 + cc2) * 64 + rr] = Tt[rr][cc2];
    }
  } else if (blk < 1670) {
    // lr3nbT chunk-gather, K-permuted: lr3nbT[m][kk*256+cc] = lrsr3[cc][pix(m,kk)] (0 off-grid).
    // Block = (pixel row y, 32-ch slice cs). LDS: 96 px (rows y-1..y+1) x 32 ch, both sides coalesced.
    float (*Px)[33] = (float(*)[33])smem;            // 96*33*4 = 12.7KB
    const int idx = blk - 1414;                      // 0..255
    const int y = idx >> 3;
    const int cs = (idx & 7) * 32;
    for (int e = tid; e < 3072; e += 256) {
      int ccq = e / 96, p = e - ccq * 96;
      int pix = (y - 1) * 32 + p;
      Px[p][ccq] = ((unsigned)pix < 1024u) ? lrsr3[(size_t)(cs + ccq) * 1024 + pix] : 0.f;
    }
    __syncthreads();
    // 32 m x 9 kk chunks of 32 ch, written 8-wide: e8 -> (mloc, kk, ccq0)
    for (int e8 = tid; e8 < 1152; e8 += 256) {
      int ccq0 = (e8 & 3) * 8;
      int r = e8 >> 2;                   // mloc*9 + kk
      int kk = r % 9, mloc = r / 9;
      int ki = kk / 3, kj = kk - ki * 3;
      int xx2 = mloc + kj - 1;
      bf8 v;
      if ((unsigned)xx2 < 32u) {
        const float* row = &Px[ki * 32 + xx2][ccq0];
#pragma unroll
        for (int e = 0; e < 8; ++e) v[e] = (short)f2bf(row[e]);
      } else {
#pragma unroll
        for (int e = 0; e < 8; ++e) v[e] = 0;
      }
      *(bf8*)(lr3nbT + (size_t)(y * 32 + mloc) * 2304 + kk * 256 + cs + ccq0) = v;
    }
  } else {
    // W transposes: output rows c'-permuted ((c%9)*Cch + c/9), output cols d'-permuted (kk2*256+cc2).
    // Tile reads 64 source rows (d = cc2*9+kk2, stride 9) x 64 cols coalesced; writes coalesced.
    unsigned short (*Ls)[65] = (unsigned short(*)[65])smem;   // 8.3KB
    int idx = blk - 1670;
    const float* W; unsigned short* Wt; int Cw, c0, kk2, cb2;
    if (idx < 648) {
      W = W1; Wt = W1t; Cw = 1152;
      int t3 = idx / 18; c0 = (idx % 18) * 64;
      kk2 = t3 >> 2; cb2 = (t3 & 3) * 64;
    } else {
      idx -= 648;
      W = W2; Wt = W2t; Cw = 576;
      int t3 = idx / 9; c0 = (idx % 9) * 64;
      kk2 = t3 >> 2; cb2 = (t3 & 3) * 64;
    }
    const int Cch = Cw / 9;
#pragma unroll
    for (int i = 0; i < 16; ++i) {
      int id = tid + i * 256;
      int r = id >> 6, c = id & 63;
      Ls[r][c] = f2bf(W[(size_t)((cb2 + r) * 9 + kk2) * Cw + c0 + c]);
    }
    __syncthreads();
#pragma unroll
    for (int i = 0; i < 16; ++i) {
      int id = tid + i * 256;
      int cc = id >> 6, rr = id & 63;
      int c = c0 + cc;
      Wt[(size_t)((c % 9) * Cch + c / 9) * 2304 + kk2 * 256 + cb2 + rr] = Ls[rr][cc];
    }
  }
}

// ---------------- bf16 MFMA GEMM body: 128x128 tile, BK=64, 4 waves ----------------
// Takes explicit smem pointer (33792B for NBUF=1) so merged kernels can union LDS.
// EPI 0: store bf16 C (rows >= Msplit scaled by rowscale map).
// EPI 1: per-(colblock,wave-half) partials (unique writer slot = bx*2+wc).
// EPI 2: per-block ninv from partials (LDS prologue), cmax stores.
struct Job {
  const unsigned short* Alo;
  const unsigned short* Ahi;
  const unsigned short* Bt;
  unsigned short* Clo;
  unsigned short* Chi;
  const float* bl;
  const float* bw;
  const float* bbp;
  const float* rowscale;
  float* pnsq;
  float* pbwd;
  float* cmax;
  int Msplit, N, K, nbx, Mtot, npart, which;
};

template <int EPI, int NBUF>
static __device__ __forceinline__ void gemm_body(const Job& j0, const Job& j1, int nb0, int bid,
                                                 unsigned char* smem) {
  unsigned short (*As)[128 * 64] = (unsigned short(*)[128 * 64])smem;
  unsigned short (*Bs)[128 * 64] = (unsigned short(*)[128 * 64])(smem + (size_t)NBUF * 16384);
  unsigned* colkey = (unsigned*)(smem + (size_t)2 * NBUF * 16384);
  float* ninvL = (float*)(smem + (size_t)2 * NBUF * 16384 + 512);

  const bool first = (bid < nb0);
  const Job j = first ? j0 : j1;
  const int local = bid - (first ? 0 : nb0);
  const int by = local / j.nbx;
  const int bx = local - by * j.nbx;
  const int m0 = by * 128, n0 = bx * 128;
  const int K = j.K, N = j.N;

  const unsigned short* Abase = (m0 < j.Msplit)
      ? j.Alo + (size_t)m0 * K
      : j.Ahi + (size_t)(m0 - j.Msplit) * K;

  const int tid = threadIdx.x;
  const int l = tid & 63;
  const int w = tid >> 6;
  const int wr = w >> 1, wc = w & 1;
  if (EPI == 2) {
    if (tid < 128) {
      colkey[tid] = 0u;
      const int r = m0 + tid;
      float nsq = 0.f, bwd = 0.f;
      for (int p = 0; p < j.npart; ++p) {
        nsq += j.pnsq[(size_t)p * j.Mtot + r];
        bwd += j.pbwd[(size_t)p * j.Mtot + r];
      }
      float tq = nsq + 2.f * bwd + j.bbp[j.which];
      ninvL[tid] = 1.f / fmaxf(sqrtf(fmaxf(tq, 0.f)), 1e-12f);
    }
  }

  f32x4 acc[4][4] = {};

  const int srow = w * 32;
  const int lrow = l >> 3;
  const int gcol = ((l & 7) ^ lrow) * 8;
  const int mr = l & 15;
  const int kg = l >> 4;

  const int nt = K >> 6;
  const int snap_kb = n0 + wc * 64;
  unsigned short snap[4][4][4];

  auto stage = [&](int buf, int kb) {
#pragma unroll
    for (int i = 0; i < 4; ++i) {
      int r = srow + i * 8;
      gload_lds16(Abase + (size_t)(r + lrow) * K + kb + gcol, &As[buf][r * 64]);
      gload_lds16(j.Bt + (size_t)(n0 + r + lrow) * K + kb + gcol, &Bs[buf][r * 64]);
    }
  };
  auto compute_tile = [&](int cur) {
#pragma unroll
    for (int ks = 0; ks < 2; ++ks) {
      bf8 af[4], bv[4];
#pragma unroll
      for (int mi = 0; mi < 4; ++mi) {
        const int row = wr * 64 + mi * 16 + mr;
        af[mi] = *(const bf8*)&As[cur][row * 64 + (((ks * 4 + kg) ^ (row & 7)) * 8)];
      }
#pragma unroll
      for (int ni = 0; ni < 4; ++ni) {
        const int row = wc * 64 + ni * 16 + mr;
        bv[ni] = *(const bf8*)&Bs[cur][row * 64 + (((ks * 4 + kg) ^ (row & 7)) * 8)];
      }
      __builtin_amdgcn_s_setprio(1);
#pragma unroll
      for (int mi = 0; mi < 4; ++mi)
#pragma unroll
        for (int ni = 0; ni < 4; ++ni)
          acc[mi][ni] = __builtin_amdgcn_mfma_f32_16x16x32_bf16(af[mi], bv[ni], acc[mi][ni], 0, 0, 0);
      __builtin_amdgcn_s_setprio(0);
    }
  };
  auto do_snap = [&](int cur) {
#pragma unroll
    for (int mi = 0; mi < 4; ++mi)
#pragma unroll
      for (int e = 0; e < 4; ++e) {
        const int row = wr * 64 + mi * 16 + kg * 4 + e;
#pragma unroll
        for (int ni = 0; ni < 4; ++ni) {
          const int slot = ni * 2 + (mr >> 3);
          snap[mi][ni][e] = As[cur][row * 64 + ((slot ^ (row & 7)) * 8) + (mr & 7)];
        }
      }
  };

  if constexpr (NBUF == 1) {
    for (int t = 0; t < nt; ++t) {
      if (t) __syncthreads();
      stage(0, t << 6);
      __syncthreads();
      compute_tile(0);
      if (EPI == 1 && (t << 6) == snap_kb) do_snap(0);
    }
  } else {
    auto waitv = [&](int Wt) {
      if (Wt >= 2)      asm volatile("s_waitcnt vmcnt(16)\ns_barrier" ::: "memory");
      else if (Wt == 1) asm volatile("s_waitcnt vmcnt(8)\ns_barrier" ::: "memory");
      else              asm volatile("s_waitcnt vmcnt(0)\ns_barrier" ::: "memory");
    };
#pragma unroll
    for (int p = 0; p < NBUF; ++p) if (p < nt) stage(p, p << 6);
    { int inflight = (NBUF < nt ? NBUF : nt); waitv(inflight - 1); }
    int cur = 0;
    for (int t = 0; t < nt; ++t) {
      compute_tile(cur);
      if (EPI == 1 && (t << 6) == snap_kb) do_snap(cur);
      if (t + 1 < nt) {
        asm volatile("s_waitcnt lgkmcnt(0)\ns_barrier" ::: "memory");
        if (t + NBUF < nt) stage(cur, (t + NBUF) << 6);
        const int im = (nt - 1 < t + NBUF) ? (nt - 1) : (t + NBUF);
        waitv(im - (t + 1));
        cur = (cur + 1 == NBUF) ? 0 : cur + 1;
      }
    }
  }

  // C/D frag layout: col = mr, row = kg*4 + e (within 16x16)
  const int lr0 = wr * 64;
  const int lc0 = wc * 64;
  if (EPI == 0) {
    const bool hi = (m0 >= j.Msplit);
    unsigned short* Cbase = hi ? j.Chi + (size_t)(m0 - j.Msplit) * N
                               : j.Clo + (size_t)m0 * N;
    float rs[4][4];
#pragma unroll
    for (int mi = 0; mi < 4; ++mi)
#pragma unroll
      for (int e = 0; e < 4; ++e)
        rs[mi][e] = hi ? j.rowscale[m0 - j.Msplit + lr0 + mi * 16 + kg * 4 + e] : 1.f;
#pragma unroll
    for (int mi = 0; mi < 4; ++mi)
#pragma unroll
      for (int ni = 0; ni < 4; ++ni)
#pragma unroll
        for (int e = 0; e < 4; ++e)
          Cbase[(size_t)(lr0 + mi * 16 + kg * 4 + e) * (size_t)N + (n0 + lc0 + ni * 16 + mr)] =
              f2bf(acc[mi][ni][e] * rs[mi][e]);
  } else if (EPI == 1) {
    float rp[4][4] = {};
    float bp[4][4] = {};
#pragma unroll
    for (int ni = 0; ni < 4; ++ni) {
      const float bwv = j.bw[n0 + lc0 + ni * 16 + mr];
#pragma unroll
      for (int mi = 0; mi < 4; ++mi)
#pragma unroll
        for (int e = 0; e < 4; ++e) {
          const float av = bf2f(snap[mi][ni][e]);
          rp[mi][e] += acc[mi][ni][e] * av;
          bp[mi][e] += bwv * av;
        }
    }
#pragma unroll
    for (int off = 1; off < 16; off <<= 1)
#pragma unroll
      for (int mi = 0; mi < 4; ++mi)
#pragma unroll
        for (int e = 0; e < 4; ++e) {
          rp[mi][e] += __shfl_xor(rp[mi][e], off);
          bp[mi][e] += __shfl_xor(bp[mi][e], off);
        }
    if (mr == 0) {
      const size_t slotbase = (size_t)(bx * 2 + wc) * j.Mtot;
#pragma unroll
      for (int mi = 0; mi < 4; ++mi)
#pragma unroll
        for (int e = 0; e < 4; ++e) {
          const int r = m0 + lr0 + mi * 16 + kg * 4 + e;
          j.pnsq[slotbase + r] = rp[mi][e];
          j.pbwd[slotbase + r] = bp[mi][e];
        }
    }
  } else {
    float nv[4][4];
#pragma unroll
    for (int mi = 0; mi < 4; ++mi)
#pragma unroll
      for (int e = 0; e < 4; ++e)
        nv[mi][e] = ninvL[lr0 + mi * 16 + kg * 4 + e];
#pragma unroll
    for (int ni = 0; ni < 4; ++ni) {
      float blv = j.bl[n0 + lc0 + ni * 16 + mr];
      float mx = -3.0e38f;
#pragma unroll
      for (int mi = 0; mi < 4; ++mi)
#pragma unroll
        for (int e = 0; e < 4; ++e) mx = fmaxf(mx, (acc[mi][ni][e] + blv) * nv[mi][e]);
      atomicMax(&colkey[lc0 + ni * 16 + mr], fkey(mx));
    }
    __syncthreads();
    if (tid < 128) j.cmax[(size_t)by * 1024 + n0 + tid] = kdec(colkey[tid]);
  }
}

// ---------------- prep dispatch B (merged with P) ----------------
// [0,218): P GEMM (EPI0, NBUF=1); [218,2522): U2b unfold; [2522,7642): U1b unfold;
// [7642,7722): bw/bb; [7722,8746): r3max; [8746,8750): bl2/bl1 window sums
__global__ __launch_bounds__(256) void k_prepBP(Job pa, Job pb, int nbP0,
                                                const float* __restrict__ rsr2t, const float* __restrict__ rsr1t,
                                                const float* __restrict__ W1, const float* __restrict__ W2,
                                                const float* __restrict__ b1, const float* __restrict__ b2,
                                                const float* __restrict__ sclw, const float* __restrict__ scu3w,
                                                const float* __restrict__ D1, const float* __restrict__ D2,
                                                const float* __restrict__ G2,
                                                unsigned short* __restrict__ U2b, unsigned short* __restrict__ U1b,
                                                float* __restrict__ bw2, float* __restrict__ bw1,
                                                float* __restrict__ bb,
                                                float* __restrict__ bl2, float* __restrict__ bl1,
                                                float* __restrict__ s3, int* __restrict__ arg) {
  __shared__ __align__(16) unsigned char sm[33792];
  const int blk = blockIdx.x;
  const int tid = threadIdx.x;
  if (blk < 218) {
    gemm_body<0, 1>(pa, pb, nbP0, xcdswz(blk, 218), sm);
  } else if (blk < 2522) {
    int id = (blk - 218) * 256 + tid;          // < 589824
    int t = id & 15, rest = id >> 4;
    int kk = rest % 9, n = rest / 9;
    int cc0 = t * 8;
    int ki = kk / 3, kj = kk - ki * 3;
    int sy = (n >> 6) + ki - 1, sx = (n & 63) + kj - 1;
    bf8 v;
    if ((unsigned)sy < 64u && (unsigned)sx < 64u) {
      const float* p = rsr2t + (size_t)(sy * 64 + sx) * 128 + cc0;
      f32x4 a = *(const f32x4*)p;
      f32x4 bq = *(const f32x4*)(p + 4);
#pragma unroll
      for (int e = 0; e < 4; ++e) { v[e] = (short)f2bf(a[e]); v[4 + e] = (short)f2bf(bq[e]); }
    } else {
#pragma unroll
      for (int e = 0; e < 8; ++e) v[e] = 0;
    }
    *(bf8*)(U2b + (size_t)n * 1152 + kk * 128 + cc0) = v;
  } else if (blk < 7642) {
    int id = (blk - 2522) * 256 + tid;         // < 1310720
    int n = id / 80, rem = id - n * 80;
    int ks = rem >> 3, t = rem & 7;
    int cc0 = t * 8;
    bf8 v;
    if (ks == 9) {
#pragma unroll
      for (int e = 0; e < 8; ++e) v[e] = 0;
    } else {
      int ki = ks / 3, kj = ks - ki * 3;
      int sy = (n >> 7) + ki - 1, sx = (n & 127) + kj - 1;
      if ((unsigned)sy < 128u && (unsigned)sx < 128u) {
        const float* p = rsr1t + (size_t)(sy * 128 + sx) * 64 + cc0;
        f32x4 a = *(const f32x4*)p;
        f32x4 bq = *(const f32x4*)(p + 4);
#pragma unroll
        for (int e = 0; e < 4; ++e) { v[e] = (short)f2bf(a[e]); v[4 + e] = (short)f2bf(bq[e]); }
      } else {
#pragma unroll
        for (int e = 0; e < 8; ++e) v[e] = 0;
      }
    }
    *(bf8*)(U1b + (size_t)n * 640 + ks * 64 + cc0) = v;
  } else if (blk < 7722) {
    float* red = (float*)sm;
    int idx = blk - 7642;
    int x = idx & 7, y = idx >> 3;             // y < 10
    if (y == 9) {
      if (x >= 2) return;
      const float* b = x ? b2 : b1;
      float s = 0.f;
      for (int d = tid; d < 2304; d += 256) s += b[d] * b[d];
      red[tid] = s; __syncthreads();
      for (int o = 128; o > 0; o >>= 1) { if (tid < o) red[tid] += red[tid + o]; __syncthreads(); }
      if (tid == 0) bb[x] = red[0];
      return;
    }
    const bool two = x < 5;
    const float* W = two ? W1 : W2;
    const float* b = two ? b1 : b2;
    float* bw = two ? bw2 : bw1;
    const int Cw = two ? 1152 : 576;
    int c = (two ? x : x - 5) * 256 + tid;
    if (c >= Cw) return;
    int d0 = y * 256;
    float s = 0.f;
    for (int d = d0; d < d0 + 256; ++d) s += b[d] * W[(size_t)d * Cw + c];
    atomicAdd(&bw[(c % 9) * (Cw / 9) + c / 9], s);   // permuted index
  } else if (blk < 8746) {
    float* bv = (float*)sm;
    int* bidx = (int*)(sm + 1024);
    const int m = blk - 7722;
    const int mi = m >> 5, mj = m & 31;
    float best = -3.0e38f; int bi = 0;
    for (int n = tid; n < 1024; n += 256) {
      const int ni = n >> 5, nj = n & 31;
      float raw = 0.f;
#pragma unroll
      for (int dy = -1; dy <= 1; ++dy) {
#pragma unroll
        for (int dx = -1; dx <= 1; ++dx) {
          bool vm = ((unsigned)(mi + dy) < 32u) && ((unsigned)(mj + dx) < 32u);
          bool vn = ((unsigned)(ni + dy) < 32u) && ((unsigned)(nj + dx) < 32u);
          if (vm && vn) {
            int off = dy * 32 + dx;
            raw += G2[(size_t)(m + off) * 1024 + (n + off)];
          }
        }
      }
      float v = raw * scu3w[n];
      if (v > best) { best = v; bi = n; }
    }
    bv[tid] = best; bidx[tid] = bi;
    __syncthreads();
    for (int o = 128; o > 0; o >>= 1) {
      if (tid < o) {
        float ov = bv[tid + o]; int oi = bidx[tid + o];
        if (ov > bv[tid] || (ov == bv[tid] && oi < bidx[tid])) { bv[tid] = ov; bidx[tid] = oi; }
      }
      __syncthreads();
    }
    if (tid == 0) { s3[m] = bv[0] * sclw[m]; arg[m] = bidx[0]; }
  } else {
    int m = (blk - 8746) * 256 + tid;          // < 1024
    int mi = m >> 5, mj = m & 31;
    float a1 = 0.f, a2 = 0.f;
#pragma unroll
    for (int ki = 0; ki < 3; ++ki) {
      int i = mi + ki - 1; if ((unsigned)i >= 32u) continue;
#pragma unroll
      for (int kj = 0; kj < 3; ++kj) {
        int jx = mj + kj - 1; if ((unsigned)jx >= 32u) continue;
        int pix = i * 32 + jx;
        int kk = ki * 3 + kj;
        a1 += D1[kk * 1024 + pix];
        a2 += D2[kk * 1024 + pix];
      }
    }
    float sc = sclw[m];
    bl2[m] = a1 * sc;
    bl1[m] = a2 * sc;
  }
}

__global__ __launch_bounds__(256) void k_gE1(Job a, Job b, int nb0) {
  __shared__ __align__(16) unsigned char sm[33792];
  gemm_body<1, 1>(a, b, nb0, xcdbal((int)blockIdx.x, (int)gridDim.x, nb0), sm);
}
__global__ __launch_bounds__(256) void k_gE2(Job a, Job b, int nb0) {
  __shared__ __align__(16) unsigned char sm[33792];
  gemm_body<2, 1>(a, b, nb0, xcdbal((int)blockIdx.x, (int)gridDim.x, nb0), sm);
}

// ---------------- fused gather+fold (vectorized) + S1/S2 finalize ----------------
__global__ __launch_bounds__(256) void k_tfold(const float* __restrict__ ref3, const float* __restrict__ ref2,
                                               const float* __restrict__ ref1, const int* __restrict__ arg,
                                               const float* __restrict__ cmax1, const float* __restrict__ cmax2,
                                               float* __restrict__ out) {
  const int bid = blockIdx.x;
  const int tid = threadIdx.x;
  if (bid < 256) {
    __shared__ float plane[1024];
    __shared__ int argL[1024];
    const int c = bid;
#pragma unroll
    for (int k = 0; k < 4; ++k) {
      plane[k * 256 + tid] = ref3[(size_t)c * 1024 + k * 256 + tid];
      argL[k * 256 + tid] = arg[k * 256 + tid];
    }
    __syncthreads();
#pragma unroll
    for (int k = 0; k < 4; ++k) {
      int px = k * 256 + tid;
      int y = px >> 5, x = px & 31;
      float s = 0.f;
#pragma unroll
      for (int di = -1; di <= 1; ++di) {
        int i = y + di;
        if ((unsigned)i >= 32u) continue;
#pragma unroll
        for (int dj = -1; dj <= 1; ++dj) {
          int jw = x + dj;
          if ((unsigned)jw >= 32u) continue;
          int n2 = argL[i * 32 + jw];
          int rr = (n2 >> 5) + y - i, cc = (n2 & 31) + x - jw;
          if ((unsigned)rr < 32u && (unsigned)cc < 32u) s += plane[rr * 32 + cc];
        }
      }
      out[3072 + (size_t)c * 1024 + px] = s * (1.f / 9.f);
    }
  } else if (bid < 1280) {
    __shared__ int argL[1024];
#pragma unroll
    for (int k = 0; k < 4; ++k) argL[k * 256 + tid] = arg[k * 256 + tid];
    __syncthreads();
    int id2 = (bid - 256) * 256 + tid;
    int q = id2 & 31, y = (id2 >> 5) & 63, c = id2 >> 11;
    int iy = y >> 1;
    float s0 = 0.f, s1 = 0.f;
#pragma unroll
    for (int di = -1; di <= 1; ++di) {
      int i = iy + di;
      if ((unsigned)i >= 32u) continue;
      int ry = y - 2 * i;
#pragma unroll
      for (int dj = -1; dj <= 1; ++dj) {
        int jw = q + dj;
        if ((unsigned)jw >= 32u) continue;
        int n2 = argL[i * 32 + jw];
        int rr = (n2 >> 5) * 2 + ry;
        int cb = (n2 & 31) * 2 + 2 * (q - jw);
        if ((unsigned)rr < 64u && (unsigned)cb < 63u) {
          const float* p = ref2 + (size_t)c * 4096 + rr * 64 + cb;
          s0 += p[0]; s1 += p[1];
        }
      }
    }
    float2 o; o.x = s0 * (1.f / 9.f); o.y = s1 * (1.f / 9.f);
    *(float2*)(out + 265216 + (size_t)c * 4096 + y * 64 + 2 * q) = o;
  } else if (bid < 2304) {
    __shared__ int argL[1024];
#pragma unroll
    for (int k = 0; k < 4; ++k) argL[k * 256 + tid] = arg[k * 256 + tid];
    __syncthreads();
    int id1 = (bid - 1280) * 256 + tid;
    int q = id1 & 31, y = (id1 >> 5) & 127, c = id1 >> 12;
    int iy = y >> 2;
    f32x4 s = {0.f, 0.f, 0.f, 0.f};
#pragma unroll
    for (int di = -1; di <= 1; ++di) {
      int i = iy + di;
      if ((unsigned)i >= 32u) continue;
      int ry = y - 4 * i;
#pragma unroll
      for (int dj = -1; dj <= 1; ++dj) {
        int jw = q + dj;
        if ((unsigned)jw >= 32u) continue;
        int n2 = argL[i * 32 + jw];
        int rr = (n2 >> 5) * 4 + ry;
        int cb = (n2 & 31) * 4 + 4 * (q - jw);
        if ((unsigned)rr < 128u && (unsigned)cb < 125u) {
          f32x4 v = *(const f32x4*)(ref1 + (size_t)c * 16384 + rr * 128 + cb);
          s += v;
        }
      }
    }
    s *= (1.f / 9.f);
    *(f32x4*)(out + 789504 + (size_t)c * 16384 + y * 128 + 4 * q) = s;
  } else {
    int t = (bid - 2304) * 256 + tid;  // 0..2047
    if (t < 1024) {
      float mx = -3.0e38f;
      for (int rb = 0; rb < 128; ++rb) mx = fmaxf(mx, cmax1[rb * 1024 + t]);
      out[t] = mx;            // S_1
    } else {
      int tt = t - 1024;
      float mx = -3.0e38f;
      for (int rb = 0; rb < 32; ++rb) mx = fmaxf(mx, cmax2[rb * 1024 + tt]);
      out[1024 + tt] = mx;    // S_2
    }
  }
}

// ---------------- workspace layout (bytes) ----------------
static constexpr size_t OFF_BW2     = 0;                        // 1152 f32
static constexpr size_t OFF_BW1     = 4608;                     // 640 f32
static constexpr size_t ZERO_BYTES  = 7168;
static constexpr size_t OFF_BB      = 7168;                     // 2 f32 (pad to 256)
static constexpr size_t OFF_BL2     = 7424;                     // 1024 f32
static constexpr size_t OFF_BL1     = 11520;                    // 1024 f32
static constexpr size_t OFF_SCLW    = 15616;                    // 1024 f32
static constexpr size_t OFF_SCU3W   = 19712;                    // 1024 f32
static constexpr size_t OFF_R3ARG   = 23808;                    // 1024 int
static constexpr size_t OFF_PNSQ2   = 27904;                    // f32 [18][4096]
static constexpr size_t OFF_PBWD2   = OFF_PNSQ2 + 294912;       // f32 [18][4096]
static constexpr size_t OFF_PNSQ1   = OFF_PBWD2 + 294912;       // f32 [10][16384]
static constexpr size_t OFF_PBWD1   = OFF_PNSQ1 + 655360;       // f32 [10][16384]
static constexpr size_t OFF_CMAX2   = OFF_PBWD1 + 655360;       // f32 [32][1024]
static constexpr size_t OFF_CMAX1   = OFF_CMAX2 + 131072;       // f32 [128][1024]
static constexpr size_t OFF_LR3NBT  = OFF_CMAX1 + 524288;       // bf16 [1024][2304] (RAW, d'-perm)
static constexpr size_t OFF_U2B     = OFF_LR3NBT + 4718592;     // bf16 [4096][1152] (perm K)
static constexpr size_t OFF_U1B     = OFF_U2B    + 9437184;     // bf16 [16384][640] (perm K)
static constexpr size_t OFF_W1T     = OFF_U1B    + 20971520;    // bf16 [1152][2304] (perm rows+cols)
static constexpr size_t OFF_W2T     = OFF_W1T    + 5308416;     // bf16 [640][2304] (perm; 576+ zero)
static constexpr size_t OFF_A2      = OFF_W2T    + 2949120;     // bf16 [1152][1152]
static constexpr size_t OFF_A1      = OFF_A2     + 2654208;     // bf16 [640][640]
static constexpr size_t OFF_M2T     = OFF_A1     + 819200;      // bf16 [1024][1152]
static constexpr size_t OFF_M1T     = OFF_M2T    + 2359296;     // bf16 [1024][640]
static constexpr size_t OFF_G2      = OFF_M1T    + 1310720;     // f32 [1024][1024]
static constexpr size_t OFF_R2T     = OFF_G2     + 4194304;     // f32 [4096][128]
static constexpr size_t OFF_R1T     = OFF_R2T    + 2097152;     // f32 [16384][64]
static constexpr size_t OFF_D1      = OFF_R1T    + 4194304;     // f32 [9][1024]
static constexpr size_t OFF_D2      = OFF_D1     + 36864;       // f32 [9][1024]

extern "C" void kernel_launch(void* const* d_in, const int* in_sizes, int n_in,
                              void* d_out, int out_size, void* d_ws, size_t ws_size,
                              hipStream_t stream) {
  (void)in_sizes; (void)n_in; (void)out_size; (void)ws_size;
  const float* lrsr3  = (const float*)d_in[0];
  const float* rsr1   = (const float*)d_in[1];
  const float* rsr2   = (const float*)d_in[2];
  const float* rsr3   = (const float*)d_in[3];
  const float* ref1   = (const float*)d_in[4];
  const float* ref2   = (const float*)d_in[5];
  const float* ref3   = (const float*)d_in[6];
  const float* W1     = (const float*)d_in[7];
  const float* b1     = (const float*)d_in[8];
  const float* W2     = (const float*)d_in[9];
  const float* b2     = (const float*)d_in[10];
  float* out = (float*)d_out;
  char* ws = (char*)d_ws;

  float*          bw2     = (float*)(ws + OFF_BW2);
  float*          bw1     = (float*)(ws + OFF_BW1);
  float*          bb      = (float*)(ws + OFF_BB);
  float*          bl2     = (float*)(ws + OFF_BL2);
  float*          bl1     = (float*)(ws + OFF_BL1);
  float*          sclw    = (float*)(ws + OFF_SCLW);
  float*          scu3w   = (float*)(ws + OFF_SCU3W);
  int*            R3arg   = (int*)(ws + OFF_R3ARG);
  float*          pnsq2   = (float*)(ws + OFF_PNSQ2);
  float*          pbwd2   = (float*)(ws + OFF_PBWD2);
  float*          pnsq1   = (float*)(ws + OFF_PNSQ1);
  float*          pbwd1   = (float*)(ws + OFF_PBWD1);
  float*          cmax2   = (float*)(ws + OFF_CMAX2);
  float*          cmax1   = (float*)(ws + OFF_CMAX1);
  unsigned short* lr3nbT  = (unsigned short*)(ws + OFF_LR3NBT);
  unsigned short* U2b     = (unsigned short*)(ws + OFF_U2B);
  unsigned short* U1b     = (unsigned short*)(ws + OFF_U1B);
  unsigned short* W1t     = (unsigned short*)(ws + OFF_W1T);
  unsigned short* W2t     = (unsigned short*)(ws + OFF_W2T);
  unsigned short* A2b     = (unsigned short*)(ws + OFF_A2);
  unsigned short* A1b     = (unsigned short*)(ws + OFF_A1);
  unsigned short* M2tb    = (unsigned short*)(ws + OFF_M2T);
  unsigned short* M1tb    = (unsigned short*)(ws + OFF_M1T);
  float*          G2      = (float*)(ws + OFF_G2);
  float*          rsr2t   = (float*)(ws + OFF_R2T);
  float*          rsr1t   = (float*)(ws + OFF_R1T);
  float*          D1      = (float*)(ws + OFF_D1);
  float*          D2      = (float*)(ws + OFF_D2);

  hipMemsetAsync(d_ws, 0, ZERO_BYTES, stream);
  // zero pad rows 576..639 of W2t
  hipMemsetAsync(ws + OFF_W2T + (size_t)576 * 2304 * 2, 0, (size_t)64 * 2304 * 2, stream);

  // A: D-maps || scale maps || pixel Gram || transposes || lr3nbT chunk-gather || W transposes
  k_prepA<<<2642, 256, 0, stream>>>(lrsr3, rsr3, rsr2, rsr1, W1, W2, b1, b2,
                                    G2, rsr2t, rsr1t, lr3nbT, W1t, W2t, sclw, scu3w, D1, D2);

  Job jz = {};
  // B+P: P-GEMM (row scale = sclw map) || U unfolds || bw/bb || r3max || bl windows
  {
    Job a = jz, b = jz;
    a.Alo = W1t; a.Ahi = lr3nbT; a.Msplit = 1152; a.Bt = W1t;
    a.Clo = A2b; a.Chi = M2tb; a.rowscale = sclw; a.N = 1152; a.K = 2304; a.nbx = 9;
    b.Alo = W2t; b.Ahi = lr3nbT; b.Msplit = 640; b.Bt = W2t;
    b.Clo = A1b; b.Chi = M1tb; b.rowscale = sclw; b.N = 640; b.K = 2304; b.nbx = 5;
    k_prepBP<<<8750, 256, 0, stream>>>(a, b, 153, rsr2t, rsr1t, W1, W2, b1, b2,
                                       sclw, scu3w, D1, D2, G2,
                                       U2b, U1b, bw2, bw1, bb, bl2, bl1, out + 2048, R3arg);
  }
  // E1: per-(colblock,half) norm/bw partials (balanced per-XCD dual-job chunking)
  {
    Job a = jz, b = jz;
    a.Alo = U2b; a.Ahi = U2b; a.Msplit = 4096; a.Bt = A2b;
    a.bw = bw2; a.pnsq = pnsq2; a.pbwd = pbwd2; a.Mtot = 4096;
    a.N = 1152; a.K = 1152; a.nbx = 9;
    b.Alo = U1b; b.Ahi = U1b; b.Msplit = 16384; b.Bt = A1b;
    b.bw = bw1; b.pnsq = pnsq1; b.pbwd = pbwd1; b.Mtot = 16384;
    b.N = 640; b.K = 640; b.nbx = 5;
    k_gE1<<<288 + 640, 256, 0, stream>>>(a, b, 288);
  }
  // E2: score max (per-block ninv from partials; balanced per-XCD dual-job chunking)
  {
    Job a = jz, b = jz;
    a.Alo = U2b; a.Ahi = U2b; a.Msplit = 4096; a.Bt = M2tb;
    a.bl = bl2; a.pnsq = pnsq2; a.pbwd = pbwd2; a.bbp = bb;
    a.npart = 18; a.which = 0; a.cmax = cmax2; a.Mtot = 4096;
    a.N = 1024; a.K = 1152; a.nbx = 8;
    b.Alo = U1b; b.Ahi = U1b; b.Msplit = 16384; b.Bt = M1tb;
    b.bl = bl1; b.pnsq = pnsq1; b.pbwd = pbwd1; b.bbp = bb;
    b.npart = 10; b.which = 1; b.cmax = cmax1; b.Mtot = 16384;
    b.N = 1024; b.K = 640; b.nbx = 8;
    k_gE2<<<256 + 1024, 256, 0, stream>>>(a, b, 256);
  }

  // transfer + S1/S2 finalize (fused, vectorized gathers)
  k_tfold<<<2312, 256, 0, stream>>>(ref3, ref2, ref1, R3arg, cmax1, cmax2, out);
}